// Round 3
// baseline (287.107 us; speedup 1.0000x reference)
//
#include <hip/hip_runtime.h>
#include <math.h>

// Problem constants
#define NTOT 4096        // H*W = 64*64
#define NBATCH 8
#define CIN 128
#define CK 64
#define CV 64
#define CO 128
#define BN_COUNT 32768.0f // B*H*W

// Workspace layout (float offsets).
#define OFF_YQ    0ul
#define OFF_YK    2097152ul
#define OFF_V     4194304ul
#define OFF_STATS 6291456ul   // [which(2)][sum/sumsq(2)][64] = 256
#define OFF_KV    6291712ul   // [8][64][64] = 32768
#define OFF_VSUM  6324480ul   // [8][64] = 512
#define OFF_M     6324992ul   // [8][64][128] (c,o) = 65536
#define OFF_D     6390528ul   // [8][128] = 1024
#define ZERO_FLOATS (256 + 32768 + 512)   // stats + KV + vsum, contiguous

// ---------------------------------------------------------------------------
// Kernel 1: 1x1 conv as GEMM for q, k (Wk,bk) and v (Wv,bv), with fused
// BN batch-stats (q,k) and vsum (v) reductions.
// grid (32 n-chunks, 8 batch, 3 tensors), block 256.
// Block tile: 64 o x 128 n, K=128 in 4 chunks of 32.
// Thread tile: 8 o x 4 n. W in LDS [k][o] (per-wave broadcast reads),
// X in LDS [k][n] (canonical conflict-free b128 reads).
// ---------------------------------------------------------------------------
__global__ __launch_bounds__(256) void gemm3_kernel(
    const float* __restrict__ Xq, const float* __restrict__ Xk, const float* __restrict__ Xv,
    const float* __restrict__ Wk, const float* __restrict__ bk,
    const float* __restrict__ Wv, const float* __restrict__ bv,
    float* __restrict__ Yq, float* __restrict__ Yk, float* __restrict__ Vv,
    float* __restrict__ stats, float* __restrict__ vsum)
{
    const int chunkn = blockIdx.x;          // 0..31
    const int b      = blockIdx.y;
    const int which  = blockIdx.z;
    const float* X    = (which == 0) ? Xq : (which == 1) ? Xk : Xv;
    const float* W    = (which == 2) ? Wv : Wk;
    const float* bias = (which == 2) ? bv : bk;
    float* Y          = (which == 0) ? Yq : (which == 1) ? Yk : Vv;

    __shared__ float sW[CIN * 64];   // [k][o], 32 KB
    __shared__ float sX[32 * 128];   // [k][n], 16 KB

    const int t  = threadIdx.x;
    const int o0 = (t >> 5) << 3;    // 0..56 step 8
    const int n0 = (t & 31) << 2;    // 0..124 step 4
    const int nblk = chunkn * 128;

    // Stage W transposed: W[o][c] -> sW[c*64+o]. One-time; write conflicts OK.
#pragma unroll
    for (int r = 0; r < 8; ++r) {
        int idx4 = t + r * 256;          // 0..2047
        int o  = idx4 >> 5;              // 0..63
        int c0 = (idx4 & 31) << 2;       // 0..124
        float4 wv = *(const float4*)(W + (size_t)o * CIN + c0);
        sW[(c0 + 0) * 64 + o] = wv.x;
        sW[(c0 + 1) * 64 + o] = wv.y;
        sW[(c0 + 2) * 64 + o] = wv.z;
        sW[(c0 + 3) * 64 + o] = wv.w;
    }

    const float* Xb = X + (size_t)b * (CIN * NTOT) + nblk;
    float acc[8][4];
#pragma unroll
    for (int oo = 0; oo < 8; ++oo)
#pragma unroll
        for (int nn = 0; nn < 4; ++nn) acc[oo][nn] = 0.f;

    for (int ck = 0; ck < 4; ++ck) {
        __syncthreads();
        // stage 32 K-rows x 128 n of X
#pragma unroll
        for (int r = 0; r < 4; ++r) {
            int idx4 = t + r * 256;      // 0..1023
            int kr = idx4 >> 5;          // 0..31
            int n4 = (idx4 & 31) << 2;   // 0..124
            float4 xv = *(const float4*)(Xb + (size_t)(ck * 32 + kr) * NTOT + n4);
            *(float4*)&sX[kr * 128 + n4] = xv;
        }
        __syncthreads();
#pragma unroll 8
        for (int k = 0; k < 32; ++k) {
            int kk = ck * 32 + k;
            float4 w0 = *(const float4*)&sW[kk * 64 + o0];
            float4 w1 = *(const float4*)&sW[kk * 64 + o0 + 4];
            float4 xv = *(const float4*)&sX[k * 128 + n0];
            float wr[8] = {w0.x, w0.y, w0.z, w0.w, w1.x, w1.y, w1.z, w1.w};
            float xr[4] = {xv.x, xv.y, xv.z, xv.w};
#pragma unroll
            for (int oo = 0; oo < 8; ++oo)
#pragma unroll
                for (int nn = 0; nn < 4; ++nn)
                    acc[oo][nn] += wr[oo] * xr[nn];
        }
    }

    // epilogue: bias + store
    float* Yb = Y + (size_t)b * (CK * NTOT) + nblk;
#pragma unroll
    for (int oo = 0; oo < 8; ++oo) {
        float bo = bias[o0 + oo];
        float4 st = make_float4(acc[oo][0] + bo, acc[oo][1] + bo,
                                acc[oo][2] + bo, acc[oo][3] + bo);
        *(float4*)&Yb[(size_t)(o0 + oo) * NTOT + n0] = st;
#pragma unroll
        for (int nn = 0; nn < 4; ++nn) acc[oo][nn] += bo;
    }

    // fused reductions. Channel o0+oo is owned exclusively by this half-wave
    // (32 lanes, t&31), so width-32 shuffle reduce then one atomic per channel.
    if (which < 2) {
        float s[8], ss[8];
#pragma unroll
        for (int oo = 0; oo < 8; ++oo) {
            float a0 = acc[oo][0], a1 = acc[oo][1], a2 = acc[oo][2], a3 = acc[oo][3];
            s[oo]  = a0 + a1 + a2 + a3;
            ss[oo] = a0 * a0 + a1 * a1 + a2 * a2 + a3 * a3;
        }
#pragma unroll
        for (int off = 16; off > 0; off >>= 1)
#pragma unroll
            for (int oo = 0; oo < 8; ++oo) {
                s[oo]  += __shfl_down(s[oo],  off, 32);
                ss[oo] += __shfl_down(ss[oo], off, 32);
            }
        if ((t & 31) == 0) {
#pragma unroll
            for (int oo = 0; oo < 8; ++oo) {
                atomicAdd(&stats[which * 128 + o0 + oo], s[oo]);
                atomicAdd(&stats[which * 128 + 64 + o0 + oo], ss[oo]);
            }
        }
    } else {
        float s[8];
#pragma unroll
        for (int oo = 0; oo < 8; ++oo)
            s[oo] = acc[oo][0] + acc[oo][1] + acc[oo][2] + acc[oo][3];
#pragma unroll
        for (int off = 16; off > 0; off >>= 1)
#pragma unroll
            for (int oo = 0; oo < 8; ++oo)
                s[oo] += __shfl_down(s[oo], off, 32);
        if ((t & 31) == 0) {
#pragma unroll
            for (int oo = 0; oo < 8; ++oo)
                atomicAdd(&vsum[b * CV + o0 + oo], s[oo]);
        }
    }
}

// ---------------------------------------------------------------------------
// Kernel 2: KV[b,c,v] = sum_n kn[b,c,n]*V[b,v,n], kn = L2-norm(BN(Yk)).
// grid (64 n-chunks, 8 batch), block 256, split-K atomics.
// BN scale/shift recomputed per block from stats (cheap).
// ---------------------------------------------------------------------------
__global__ __launch_bounds__(256) void kv_kernel(
    const float* __restrict__ Yk, const float* __restrict__ Vv,
    const float* __restrict__ stats,
    const float* __restrict__ gamma, const float* __restrict__ beta,
    float* __restrict__ KV)
{
    const int chunk = blockIdx.x;
    const int b     = blockIdx.y;
    __shared__ float sk[64][65];
    __shared__ float sv[64][65];
    __shared__ float rn[64];
    __shared__ float kscl[64], kshf[64];

    const int t = threadIdx.x;
    if (t < 64) {
        float S = stats[128 + t], SS = stats[192 + t];
        float mean = S * (1.f / BN_COUNT);
        float var  = SS * (1.f / BN_COUNT) - mean * mean;
        float scl = gamma[t] * rsqrtf(var + 1e-5f);
        kscl[t] = scl;
        kshf[t] = beta[t] - mean * scl;
    }
    __syncthreads();

    const int n0 = chunk * 64;
    const float* Ykb = Yk + (size_t)b * (CK * NTOT) + n0;
    const float* Vb  = Vv + (size_t)b * (CK * NTOT) + n0;

#pragma unroll
    for (int r = 0; r < 4; ++r) {
        int idx4 = t + r * 256;
        int c  = idx4 >> 4;
        int j4 = (idx4 & 15) << 2;
        float4 kf = *(const float4*)(Ykb + (size_t)c * NTOT + j4);
        float4 vf = *(const float4*)(Vb  + (size_t)c * NTOT + j4);
        float scl = kscl[c], sh = kshf[c];
        sk[c][j4 + 0] = kf.x * scl + sh;
        sk[c][j4 + 1] = kf.y * scl + sh;
        sk[c][j4 + 2] = kf.z * scl + sh;
        sk[c][j4 + 3] = kf.w * scl + sh;
        sv[c][j4 + 0] = vf.x; sv[c][j4 + 1] = vf.y;
        sv[c][j4 + 2] = vf.z; sv[c][j4 + 3] = vf.w;
    }
    __syncthreads();
    if (t < 64) {
        float ssum = 0.f;
#pragma unroll 8
        for (int c = 0; c < 64; ++c) { float x = sk[c][t]; ssum += x * x; }
        rn[t] = 1.f / (sqrtf(ssum) + 1e-7f);
    }
    __syncthreads();
#pragma unroll
    for (int r = 0; r < 16; ++r) {
        int idx = t + r * 256;
        sk[idx >> 6][idx & 63] *= rn[idx & 63];
    }
    __syncthreads();

    const int tc = t >> 4, tv = t & 15;
    float acc[4][4];
#pragma unroll
    for (int i = 0; i < 4; ++i)
#pragma unroll
        for (int k2 = 0; k2 < 4; ++k2) acc[i][k2] = 0.f;

#pragma unroll 4
    for (int j = 0; j < 64; ++j) {
        float a[4], bb[4];
#pragma unroll
        for (int i = 0; i < 4; ++i) a[i]  = sk[tc * 4 + i][j];
#pragma unroll
        for (int i = 0; i < 4; ++i) bb[i] = sv[tv * 4 + i][j];
#pragma unroll
        for (int i = 0; i < 4; ++i)
#pragma unroll
            for (int k2 = 0; k2 < 4; ++k2) acc[i][k2] += a[i] * bb[k2];
    }

    float* KVb = KV + b * (CK * CV);
#pragma unroll
    for (int i = 0; i < 4; ++i)
#pragma unroll
        for (int k2 = 0; k2 < 4; ++k2)
            atomicAdd(&KVb[(tc * 4 + i) * CV + tv * 4 + k2], acc[i][k2]);
}

// ---------------------------------------------------------------------------
// Kernel 3: M[b,c,o] = sum_v KV[b,c,v]*Ww[o,v];  d[b,o] = bw[o] + Ww·vsum
// grid 8 (batch), block 256.
// ---------------------------------------------------------------------------
__global__ __launch_bounds__(256) void m_kernel(
    const float* __restrict__ KV, const float* __restrict__ vsum,
    const float* __restrict__ Ww, const float* __restrict__ bw,
    float* __restrict__ M, float* __restrict__ d)
{
    const int b = blockIdx.x;
    __shared__ float sKV[64][65];
    __shared__ float sWw[128][65];
    __shared__ float svs[64];
    const int t = threadIdx.x;

#pragma unroll
    for (int r = 0; r < 16; ++r) {
        int idx = t + r * 256;                       // 0..4095
        sKV[idx >> 6][idx & 63] = KV[b * (CK * CV) + idx];
    }
#pragma unroll
    for (int r = 0; r < 32; ++r) {
        int idx = t + r * 256;                       // 0..8191
        sWw[idx >> 6][idx & 63] = Ww[idx];
    }
    if (t < 64) svs[t] = vsum[b * CV + t];
    __syncthreads();

#pragma unroll
    for (int r = 0; r < 32; ++r) {
        int idx = t + r * 256;
        int c = idx >> 7, o = idx & 127;
        float acc = 0.f;
#pragma unroll 16
        for (int v = 0; v < 64; ++v) acc += sKV[c][v] * sWw[o][v];
        M[(size_t)b * (CK * CO) + idx] = acc;
    }
    if (t < 128) {
        float acc = bw[t];
#pragma unroll 16
        for (int v = 0; v < 64; ++v) acc += sWw[t][v] * svs[v];
        d[b * CO + t] = acc;
    }
}

// ---------------------------------------------------------------------------
// Kernel 4: out[b,o,n] = d[b,o] + sum_c qn[b,c,n] * M[b,c,o]
// qn = L2-norm(BN(Yq)). grid (64 n-chunks, 8 batch), block 256.
// ---------------------------------------------------------------------------
__global__ __launch_bounds__(256) void out_kernel(
    const float* __restrict__ Yq,
    const float* __restrict__ stats,
    const float* __restrict__ gamma, const float* __restrict__ beta,
    const float* __restrict__ M, const float* __restrict__ d,
    float* __restrict__ out)
{
    const int chunk = blockIdx.x;
    const int b     = blockIdx.y;
    __shared__ float sM[CK * CO];    // [c][o] flat, 32 KB
    __shared__ float sq[64][68];
    __shared__ float rn[64];
    __shared__ float sd[CO];
    __shared__ float qscl[64], qshf[64];

    const int t = threadIdx.x;
    const int n0 = chunk * 64;

    if (t < 64) {
        float S = stats[t], SS = stats[64 + t];
        float mean = S * (1.f / BN_COUNT);
        float var  = SS * (1.f / BN_COUNT) - mean * mean;
        float scl = gamma[t] * rsqrtf(var + 1e-5f);
        qscl[t] = scl;
        qshf[t] = beta[t] - mean * scl;
    }

#pragma unroll
    for (int r = 0; r < 8; ++r) {
        int idx4 = t + r * 256;
        ((float4*)sM)[idx4] = ((const float4*)(M + (size_t)b * (CK * CO)))[idx4];
    }
    if (t < CO) sd[t] = d[b * CO + t];
    __syncthreads();

    const float* Yb = Yq + (size_t)b * (CK * NTOT) + n0;
#pragma unroll
    for (int r = 0; r < 4; ++r) {
        int idx4 = t + r * 256;
        int c  = idx4 >> 4;
        int j4 = (idx4 & 15) << 2;
        float4 xv = *(const float4*)(Yb + (size_t)c * NTOT + j4);
        float scl = qscl[c], sh = qshf[c];
        sq[c][j4 + 0] = xv.x * scl + sh;
        sq[c][j4 + 1] = xv.y * scl + sh;
        sq[c][j4 + 2] = xv.z * scl + sh;
        sq[c][j4 + 3] = xv.w * scl + sh;
    }
    __syncthreads();
    if (t < 64) {
        float ssum = 0.f;
#pragma unroll 8
        for (int c = 0; c < 64; ++c) { float x = sq[c][t]; ssum += x * x; }
        rn[t] = 1.f / (sqrtf(ssum) + 1e-7f);
    }
    __syncthreads();
#pragma unroll
    for (int r = 0; r < 16; ++r) {
        int idx = t + r * 256;
        sq[idx >> 6][idx & 63] *= rn[idx & 63];
    }
    __syncthreads();

    const int j0 = (t & 15) << 2;       // 4 columns
    const int o0 = (t >> 4) << 3;       // 8 out-channels
    float acc[4][8];
#pragma unroll
    for (int jj = 0; jj < 4; ++jj)
#pragma unroll
        for (int oo = 0; oo < 8; ++oo) acc[jj][oo] = sd[o0 + oo];

#pragma unroll 4
    for (int c = 0; c < 64; ++c) {
        float4 qv = *(const float4*)&sq[c][j0];
        float4 m0 = *(const float4*)&sM[c * CO + o0];
        float4 m1 = *(const float4*)&sM[c * CO + o0 + 4];
        float aq[4] = {qv.x, qv.y, qv.z, qv.w};
        float am[8] = {m0.x, m0.y, m0.z, m0.w, m1.x, m1.y, m1.z, m1.w};
#pragma unroll
        for (int jj = 0; jj < 4; ++jj)
#pragma unroll
            for (int oo = 0; oo < 8; ++oo) acc[jj][oo] += aq[jj] * am[oo];
    }

    float* outb = out + (size_t)b * (CO * NTOT) + n0;
#pragma unroll
    for (int oo = 0; oo < 8; ++oo) {
        float4 st = make_float4(acc[0][oo], acc[1][oo], acc[2][oo], acc[3][oo]);
        *(float4*)&outb[(size_t)(o0 + oo) * NTOT + j0] = st;
    }
}

// ---------------------------------------------------------------------------
extern "C" void kernel_launch(void* const* d_in, const int* in_sizes, int n_in,
                              void* d_out, int out_size, void* d_ws, size_t ws_size,
                              hipStream_t stream) {
    (void)in_sizes; (void)n_in; (void)out_size; (void)ws_size;
    const float* q     = (const float*)d_in[0];
    const float* k     = (const float*)d_in[1];
    const float* v     = (const float*)d_in[2];
    const float* Wk    = (const float*)d_in[3];
    const float* bk    = (const float*)d_in[4];
    const float* gamma = (const float*)d_in[5];
    const float* beta  = (const float*)d_in[6];
    const float* Wv    = (const float*)d_in[7];
    const float* bv    = (const float*)d_in[8];
    const float* Ww    = (const float*)d_in[9];
    const float* bw    = (const float*)d_in[10];
    float* out = (float*)d_out;
    float* ws  = (float*)d_ws;

    float* Yq    = ws + OFF_YQ;
    float* Yk    = ws + OFF_YK;
    float* Vv    = ws + OFF_V;
    float* stats = ws + OFF_STATS;
    float* KV    = ws + OFF_KV;
    float* vsum  = ws + OFF_VSUM;
    float* M     = ws + OFF_M;
    float* dd    = ws + OFF_D;

    // zero stats + KV + vsum (contiguous; ws is re-poisoned before every call)
    hipMemsetAsync(stats, 0, ZERO_FLOATS * sizeof(float), stream);

    gemm3_kernel<<<dim3(32, NBATCH, 3), 256, 0, stream>>>(
        q, k, v, Wk, bk, Wv, bv, Yq, Yk, Vv, stats, vsum);
    kv_kernel<<<dim3(64, NBATCH), 256, 0, stream>>>(Yk, Vv, stats, gamma, beta, KV);
    m_kernel<<<NBATCH, 256, 0, stream>>>(KV, vsum, Ww, bw, M, dd);
    out_kernel<<<dim3(64, NBATCH), 256, 0, stream>>>(Yq, stats, gamma, beta, M, dd, out);
}

// Round 4
// 256.633 us; speedup vs baseline: 1.1187x; 1.1187x over previous
//
#include <hip/hip_runtime.h>
#include <math.h>

// Problem constants
#define NTOT 4096        // H*W = 64*64
#define NBATCH 8
#define CIN 128
#define CK 64
#define CV 64
#define CO 128
#define BN_COUNT 32768.0f // B*H*W

// Workspace layout (float offsets).
#define OFF_YQ    0ul
#define OFF_YK    2097152ul
#define OFF_V     4194304ul
#define OFF_STATS 6291456ul   // [which(2)][sum/sumsq(2)][64] = 256
#define OFF_KV    6291712ul   // [8][64][64] = 32768
#define OFF_VSUM  6324480ul   // [8][64] = 512
#define OFF_M     6324992ul   // [8][64][128] (c,o) = 65536
#define OFF_D     6390528ul   // [8][128] = 1024
#define ZERO_FLOATS (256 + 32768 + 512)   // stats + KV + vsum, contiguous

// ---------------------------------------------------------------------------
// Kernel 1: 1x1 conv GEMM for q,k (Wk,bk) and v (Wv,bv) + fused BN-stats/vsum.
// grid (32 n-chunks, 8 batch, 3 tensors), block 256. Tile 64o x 128n.
// Thread: 8 o (strided: o = (t>>5) + 8*oo -> W reads are wave-half-uniform
// BROADCASTS, conflict-free with natural [o][k] layout) x 4 n (consecutive,
// canonical b128 X reads/stores). K in 4 chunks of 32; LDS 24 KB.
// ---------------------------------------------------------------------------
__global__ __launch_bounds__(256) void gemm3_kernel(
    const float* __restrict__ Xq, const float* __restrict__ Xk, const float* __restrict__ Xv,
    const float* __restrict__ Wk, const float* __restrict__ bk,
    const float* __restrict__ Wv, const float* __restrict__ bv,
    float* __restrict__ Yq, float* __restrict__ Yk, float* __restrict__ Vv,
    float* __restrict__ stats, float* __restrict__ vsum)
{
    const int chunkn = blockIdx.x;          // 0..31
    const int b      = blockIdx.y;
    const int which  = blockIdx.z;
    const float* X    = (which == 0) ? Xq : (which == 1) ? Xk : Xv;
    const float* W    = (which == 2) ? Wv : Wk;
    const float* bias = (which == 2) ? bv : bk;
    float* Y          = (which == 0) ? Yq : (which == 1) ? Yk : Vv;

    __shared__ float sW[64 * 32];    // [o][k-in-chunk], 8 KB, natural layout
    __shared__ float sX[32 * 128];   // [k][n], 16 KB

    const int t  = threadIdx.x;
    const int g  = t >> 5;           // o-group 0..7 (uniform per half-wave)
    const int n0 = (t & 31) << 2;    // 0..124
    const int nblk = chunkn * 128;

    const float* Xb = X + (size_t)b * (CIN * NTOT) + nblk;
    float acc[8][4];
#pragma unroll
    for (int oo = 0; oo < 8; ++oo)
#pragma unroll
        for (int nn = 0; nn < 4; ++nn) acc[oo][nn] = 0.f;

    for (int ck = 0; ck < 4; ++ck) {
        __syncthreads();
        // stage W chunk: 64o x 32k = 512 float4 (consecutive writes)
#pragma unroll
        for (int r = 0; r < 2; ++r) {
            int idx4 = t + r * 256;          // 0..511
            int o  = idx4 >> 3;              // 0..63
            int c4 = (idx4 & 7) << 2;        // 0..28
            float4 wv = *(const float4*)(W + (size_t)o * CIN + ck * 32 + c4);
            *(float4*)&sW[o * 32 + c4] = wv;
        }
        // stage X chunk: 32k x 128n = 1024 float4 (consecutive writes)
#pragma unroll
        for (int r = 0; r < 4; ++r) {
            int idx4 = t + r * 256;          // 0..1023
            int kr = idx4 >> 5;              // 0..31
            int n4 = (idx4 & 31) << 2;       // 0..124
            *(float4*)&sX[kr * 128 + n4] =
                *(const float4*)(Xb + (size_t)(ck * 32 + kr) * NTOT + n4);
        }
        __syncthreads();
#pragma unroll
        for (int kk = 0; kk < 8; ++kk) {     // 4 k per iter
            float4 x[4];
#pragma unroll
            for (int kq = 0; kq < 4; ++kq)
                x[kq] = *(const float4*)&sX[(kk * 4 + kq) * 128 + n0];
#pragma unroll
            for (int oo = 0; oo < 8; ++oo) {
                float4 w = *(const float4*)&sW[(g + 8 * oo) * 32 + kk * 4]; // broadcast
                float wr[4] = {w.x, w.y, w.z, w.w};
                float xr[4][4] = {
                    {x[0].x, x[0].y, x[0].z, x[0].w},
                    {x[1].x, x[1].y, x[1].z, x[1].w},
                    {x[2].x, x[2].y, x[2].z, x[2].w},
                    {x[3].x, x[3].y, x[3].z, x[3].w}};
#pragma unroll
                for (int kq = 0; kq < 4; ++kq)
#pragma unroll
                    for (int nn = 0; nn < 4; ++nn)
                        acc[oo][nn] += wr[kq] * xr[kq][nn];
            }
        }
    }

    // epilogue: bias + store (coalesced b128)
    float* Yb = Y + (size_t)b * (CK * NTOT) + nblk;
#pragma unroll
    for (int oo = 0; oo < 8; ++oo) {
        int o = g + 8 * oo;
        float bo = bias[o];
#pragma unroll
        for (int nn = 0; nn < 4; ++nn) acc[oo][nn] += bo;
        *(float4*)&Yb[(size_t)o * NTOT + n0] =
            make_float4(acc[oo][0], acc[oo][1], acc[oo][2], acc[oo][3]);
    }

    // fused reductions: channel o = g+8*oo owned by 32 consecutive lanes.
    if (which < 2) {
        float s[8], ss[8];
#pragma unroll
        for (int oo = 0; oo < 8; ++oo) {
            float a0 = acc[oo][0], a1 = acc[oo][1], a2 = acc[oo][2], a3 = acc[oo][3];
            s[oo]  = a0 + a1 + a2 + a3;
            ss[oo] = a0 * a0 + a1 * a1 + a2 * a2 + a3 * a3;
        }
#pragma unroll
        for (int off = 16; off > 0; off >>= 1)
#pragma unroll
            for (int oo = 0; oo < 8; ++oo) {
                s[oo]  += __shfl_down(s[oo],  off, 32);
                ss[oo] += __shfl_down(ss[oo], off, 32);
            }
        if ((t & 31) == 0) {
#pragma unroll
            for (int oo = 0; oo < 8; ++oo) {
                atomicAdd(&stats[which * 128 + g + 8 * oo], s[oo]);
                atomicAdd(&stats[which * 128 + 64 + g + 8 * oo], ss[oo]);
            }
        }
    } else {
        float s[8];
#pragma unroll
        for (int oo = 0; oo < 8; ++oo)
            s[oo] = acc[oo][0] + acc[oo][1] + acc[oo][2] + acc[oo][3];
#pragma unroll
        for (int off = 16; off > 0; off >>= 1)
#pragma unroll
            for (int oo = 0; oo < 8; ++oo)
                s[oo] += __shfl_down(s[oo], off, 32);
        if ((t & 31) == 0) {
#pragma unroll
            for (int oo = 0; oo < 8; ++oo)
                atomicAdd(&vsum[b * CV + g + 8 * oo], s[oo]);
        }
    }
}

// ---------------------------------------------------------------------------
// Kernel 2: KV[b,c,v] = sum_n kn[b,c,n]*V[b,v,n], kn = L2-norm(BN(Yk)).
// grid (64 n-chunks, 8 batch), block 256, split-K atomics.
// Row pad 69: (4*tv)*69 = 20*tv mod 32 -> 2-way (free) on the sv j-loop reads.
// Column norm parallelized across all 4 waves; rn folded into j-loop.
// ---------------------------------------------------------------------------
__global__ __launch_bounds__(256) void kv_kernel(
    const float* __restrict__ Yk, const float* __restrict__ Vv,
    const float* __restrict__ stats,
    const float* __restrict__ gamma, const float* __restrict__ beta,
    float* __restrict__ KV)
{
    const int chunk = blockIdx.x;
    const int b     = blockIdx.y;
    __shared__ float sk[64 * 69];
    __shared__ float sv[64 * 69];
    __shared__ float rnp[4][64];
    __shared__ float rn[64];
    __shared__ float kscl[64], kshf[64];

    const int t = threadIdx.x;
    if (t < 64) {
        float S = stats[128 + t], SS = stats[192 + t];
        float mean = S * (1.f / BN_COUNT);
        float var  = SS * (1.f / BN_COUNT) - mean * mean;
        float scl = gamma[t] * rsqrtf(var + 1e-5f);
        kscl[t] = scl;
        kshf[t] = beta[t] - mean * scl;
    }
    __syncthreads();

    const int n0 = chunk * 64;
    const float* Ykb = Yk + (size_t)b * (CK * NTOT) + n0;
    const float* Vb  = Vv + (size_t)b * (CK * NTOT) + n0;

#pragma unroll
    for (int r = 0; r < 4; ++r) {
        int idx4 = t + r * 256;
        int c  = idx4 >> 4;
        int j4 = (idx4 & 15) << 2;
        float4 kf = *(const float4*)(Ykb + (size_t)c * NTOT + j4);
        float4 vf = *(const float4*)(Vb  + (size_t)c * NTOT + j4);
        float scl = kscl[c], sh = kshf[c];
        sk[c * 69 + j4 + 0] = kf.x * scl + sh;
        sk[c * 69 + j4 + 1] = kf.y * scl + sh;
        sk[c * 69 + j4 + 2] = kf.z * scl + sh;
        sk[c * 69 + j4 + 3] = kf.w * scl + sh;
        sv[c * 69 + j4 + 0] = vf.x; sv[c * 69 + j4 + 1] = vf.y;
        sv[c * 69 + j4 + 2] = vf.z; sv[c * 69 + j4 + 3] = vf.w;
    }
    __syncthreads();
    // column sumsq partials: wave w covers c in [16w,16w+16), thread's n = t&63
    {
        int n = t & 63, w = t >> 6;
        float ps = 0.f;
#pragma unroll
        for (int i = 0; i < 16; ++i) {
            float x = sk[(w * 16 + i) * 69 + n];
            ps += x * x;
        }
        rnp[w][n] = ps;
    }
    __syncthreads();
    if (t < 64) {
        float rs = rnp[0][t] + rnp[1][t] + rnp[2][t] + rnp[3][t];
        rn[t] = 1.f / (sqrtf(rs) + 1e-7f);
    }
    __syncthreads();

    const int tc = t >> 4, tv = t & 15;
    float acc[4][4];
#pragma unroll
    for (int i = 0; i < 4; ++i)
#pragma unroll
        for (int k2 = 0; k2 < 4; ++k2) acc[i][k2] = 0.f;

#pragma unroll 4
    for (int j = 0; j < 64; ++j) {
        float arn = rn[j];
        float a[4], bb[4];
#pragma unroll
        for (int i = 0; i < 4; ++i) a[i]  = sk[(tc * 4 + i) * 69 + j] * arn;
#pragma unroll
        for (int i = 0; i < 4; ++i) bb[i] = sv[(tv * 4 + i) * 69 + j];
#pragma unroll
        for (int i = 0; i < 4; ++i)
#pragma unroll
            for (int k2 = 0; k2 < 4; ++k2) acc[i][k2] += a[i] * bb[k2];
    }

    float* KVb = KV + b * (CK * CV);
#pragma unroll
    for (int i = 0; i < 4; ++i)
#pragma unroll
        for (int k2 = 0; k2 < 4; ++k2)
            atomicAdd(&KVb[(tc * 4 + i) * CV + tv * 4 + k2], acc[i][k2]);
}

// ---------------------------------------------------------------------------
// Kernel 3: M[b,c,o] = sum_v KV[b,c,v]*Ww[o,v];  d[b,o] = bw[o] + Ww·vsum
// grid (8 o-slices, 8 batch), block 256; each block: 64c x 16o.
// ---------------------------------------------------------------------------
__global__ __launch_bounds__(256) void m_kernel(
    const float* __restrict__ KV, const float* __restrict__ vsum,
    const float* __restrict__ Ww, const float* __restrict__ bw,
    float* __restrict__ M, float* __restrict__ d)
{
    const int och = blockIdx.x;       // 0..7, o-slice of 16
    const int b   = blockIdx.y;
    __shared__ float sKV[64 * 65];
    __shared__ float sWw[16 * 68];
    __shared__ float svs[64];
    const int t = threadIdx.x;

#pragma unroll
    for (int r = 0; r < 16; ++r) {
        int idx = t + r * 256;                       // 0..4095
        sKV[(idx >> 6) * 65 + (idx & 63)] = KV[b * (CK * CV) + idx];
    }
    {   // 16 o-rows x 64 v = 256 float4
        int o16 = t >> 4, v4 = (t & 15) << 2;
        float4 wv = *(const float4*)(Ww + (size_t)(och * 16 + o16) * CV + v4);
        *(float4*)&sWw[o16 * 68 + v4] = wv;
    }
    if (t < 64) svs[t] = vsum[b * CV + t];
    __syncthreads();

#pragma unroll
    for (int r = 0; r < 4; ++r) {
        int idx = t + r * 256;                       // 0..1023
        int c = idx >> 4, o16 = idx & 15;
        float acc = 0.f;
#pragma unroll 16
        for (int v = 0; v < 64; ++v) acc += sKV[c * 65 + v] * sWw[o16 * 68 + v];
        M[(size_t)b * (CK * CO) + (size_t)c * CO + och * 16 + o16] = acc;
    }
    if (t < 16) {
        int o = och * 16 + t;
        float acc = bw[o];
#pragma unroll 16
        for (int v = 0; v < 64; ++v) acc += sWw[t * 68 + v] * svs[v];
        d[b * CO + o] = acc;
    }
}

// ---------------------------------------------------------------------------
// Kernel 4: out[b,o,n] = rn_n * (sum_c qhat[b,c,n]*M[b,c,o]) + d[b,o]
// qhat = BN(Yq) (un-normalized; rn factored to epilogue).
// grid (64 n-chunks, 8 batch), block 256. Thread: 4n x 8o.
// ---------------------------------------------------------------------------
__global__ __launch_bounds__(256) void out_kernel(
    const float* __restrict__ Yq,
    const float* __restrict__ stats,
    const float* __restrict__ gamma, const float* __restrict__ beta,
    const float* __restrict__ M, const float* __restrict__ d,
    float* __restrict__ out)
{
    const int chunk = blockIdx.x;
    const int b     = blockIdx.y;
    __shared__ float sM[CK * CO];     // [c][o], 32 KB
    __shared__ float sq[64 * 68];     // padded, float4-aligned rows (272 B)
    __shared__ float rnp[4][64];
    __shared__ float sd[CO];
    __shared__ float qscl[64], qshf[64];

    const int t = threadIdx.x;
    const int n0 = chunk * 64;

    if (t < 64) {
        float S = stats[t], SS = stats[64 + t];
        float mean = S * (1.f / BN_COUNT);
        float var  = SS * (1.f / BN_COUNT) - mean * mean;
        float scl = gamma[t] * rsqrtf(var + 1e-5f);
        qscl[t] = scl;
        qshf[t] = beta[t] - mean * scl;
    }
    if (t < CO) sd[t] = d[b * CO + t];
    __syncthreads();

#pragma unroll
    for (int r = 0; r < 8; ++r) {
        int idx4 = t + r * 256;
        ((float4*)sM)[idx4] = ((const float4*)(M + (size_t)b * (CK * CO)))[idx4];
    }
    const float* Yb = Yq + (size_t)b * (CK * NTOT) + n0;
#pragma unroll
    for (int r = 0; r < 4; ++r) {
        int idx4 = t + r * 256;
        int c  = idx4 >> 4;
        int j4 = (idx4 & 15) << 2;
        float4 xv = *(const float4*)(Yb + (size_t)c * NTOT + j4);
        float scl = qscl[c], sh = qshf[c];
        *(float4*)&sq[c * 68 + j4] = make_float4(
            xv.x * scl + sh, xv.y * scl + sh, xv.z * scl + sh, xv.w * scl + sh);
    }
    __syncthreads();
    {   // column sumsq partials across all 4 waves
        int n = t & 63, w = t >> 6;
        float ps = 0.f;
#pragma unroll
        for (int i = 0; i < 16; ++i) {
            float x = sq[(w * 16 + i) * 68 + n];
            ps += x * x;
        }
        rnp[w][n] = ps;
    }
    __syncthreads();

    const int j0 = (t & 15) << 2;       // 4 columns
    const int o0 = (t >> 4) << 3;       // 8 out-channels
    float acc[4][8];
#pragma unroll
    for (int jj = 0; jj < 4; ++jj)
#pragma unroll
        for (int oo = 0; oo < 8; ++oo) acc[jj][oo] = 0.f;

#pragma unroll 4
    for (int c = 0; c < 64; ++c) {
        float4 qv = *(const float4*)&sq[c * 68 + j0];
        float4 m0 = *(const float4*)&sM[c * CO + o0];
        float4 m1 = *(const float4*)&sM[c * CO + o0 + 4];
        float aq[4] = {qv.x, qv.y, qv.z, qv.w};
        float am[8] = {m0.x, m0.y, m0.z, m0.w, m1.x, m1.y, m1.z, m1.w};
#pragma unroll
        for (int jj = 0; jj < 4; ++jj)
#pragma unroll
            for (int oo = 0; oo < 8; ++oo) acc[jj][oo] += aq[jj] * am[oo];
    }

    // epilogue: apply per-column rn and bias d
    float rnj[4];
#pragma unroll
    for (int jj = 0; jj < 4; ++jj) {
        int j = j0 + jj;
        float rs = rnp[0][j] + rnp[1][j] + rnp[2][j] + rnp[3][j];
        rnj[jj] = 1.f / (sqrtf(rs) + 1e-7f);
    }
    float* outb = out + (size_t)b * (CO * NTOT) + n0;
#pragma unroll
    for (int oo = 0; oo < 8; ++oo) {
        float dv = sd[o0 + oo];
        float4 st = make_float4(acc[0][oo] * rnj[0] + dv, acc[1][oo] * rnj[1] + dv,
                                acc[2][oo] * rnj[2] + dv, acc[3][oo] * rnj[3] + dv);
        *(float4*)&outb[(size_t)(o0 + oo) * NTOT + j0] = st;
    }
}

// ---------------------------------------------------------------------------
extern "C" void kernel_launch(void* const* d_in, const int* in_sizes, int n_in,
                              void* d_out, int out_size, void* d_ws, size_t ws_size,
                              hipStream_t stream) {
    (void)in_sizes; (void)n_in; (void)out_size; (void)ws_size;
    const float* q     = (const float*)d_in[0];
    const float* k     = (const float*)d_in[1];
    const float* v     = (const float*)d_in[2];
    const float* Wk    = (const float*)d_in[3];
    const float* bk    = (const float*)d_in[4];
    const float* gamma = (const float*)d_in[5];
    const float* beta  = (const float*)d_in[6];
    const float* Wv    = (const float*)d_in[7];
    const float* bv    = (const float*)d_in[8];
    const float* Ww    = (const float*)d_in[9];
    const float* bw    = (const float*)d_in[10];
    float* out = (float*)d_out;
    float* ws  = (float*)d_ws;

    float* Yq    = ws + OFF_YQ;
    float* Yk    = ws + OFF_YK;
    float* Vv    = ws + OFF_V;
    float* stats = ws + OFF_STATS;
    float* KV    = ws + OFF_KV;
    float* vsum  = ws + OFF_VSUM;
    float* M     = ws + OFF_M;
    float* dd    = ws + OFF_D;

    // zero stats + KV + vsum (contiguous; ws is re-poisoned before every call)
    hipMemsetAsync(stats, 0, ZERO_FLOATS * sizeof(float), stream);

    gemm3_kernel<<<dim3(32, NBATCH, 3), 256, 0, stream>>>(
        q, k, v, Wk, bk, Wv, bv, Yq, Yk, Vv, stats, vsum);
    kv_kernel<<<dim3(64, NBATCH), 256, 0, stream>>>(Yk, Vv, stats, gamma, beta, KV);
    m_kernel<<<dim3(8, NBATCH), 256, 0, stream>>>(KV, vsum, Ww, bw, M, dd);
    out_kernel<<<dim3(64, NBATCH), 256, 0, stream>>>(Yq, stats, gamma, beta, M, dd, out);
}